// Round 12
// baseline (373.402 us; speedup 1.0000x reference)
//
#include <hip/hip_runtime.h>
#include <hip/hip_bf16.h>
#include <stdint.h>
#include <stddef.h>

#define NEG 0.1f

typedef __attribute__((ext_vector_type(8))) short short8;
typedef __attribute__((ext_vector_type(16))) float floatx16;

__device__ __forceinline__ unsigned f2bf(float f) {
  union { float f; unsigned u; } v; v.f = f;
  unsigned r = v.u + 0x7FFFu + ((v.u >> 16) & 1u);   // RNE
  return r >> 16;
}
__device__ __forceinline__ unsigned pk2bf(float a, float b) {   // a->low16, b->high16
  __hip_bfloat162 hh = __float22bfloat162_rn(make_float2(a, b));
  union { __hip_bfloat162 h; unsigned u; } v; v.h = hh; return v.u;
}
__device__ __forceinline__ float bits2f(unsigned u) {
  union { unsigned u; float f; } v; v.u = u; return v.f;
}

// frag-order index for B-operand tiles: element (row f = ct*32+i32,
// col kcol = cg*64 + kk*16 + h*8 + j) ->
//   (((ct*NC + cg)*4 + kk)*2 + h)*256 + i32*8 + j

// ---------------- fused prep: conv-w frag-order | wab frag-order | wmlp |
//                  hc (direct) | ws zero
__global__ void k_prep(const float* __restrict__ cw1, const float* __restrict__ cw2,
                       const float* __restrict__ cw3, const float* __restrict__ cw4,
                       unsigned short* __restrict__ wt1, unsigned short* __restrict__ wt2,
                       unsigned short* __restrict__ wt3, unsigned short* __restrict__ wt4,
                       const float* __restrict__ W1, unsigned short* __restrict__ wabf,
                       const float* __restrict__ W2, const float* __restrict__ W3,
                       const float* __restrict__ W4, unsigned short* __restrict__ wmlp,
                       const float* __restrict__ h, float* __restrict__ hc,
                       float* __restrict__ zmem) {
  __shared__ float tile[256];
  int bid = blockIdx.x, tid = threadIdx.x;
  if (bid < 1280) {                       // conv weights -> frag order
    int z = bid;
    int E; const float* cw; unsigned short* wt;
    if (z < 512) { E = 512; cw = cw1; wt = wt1; }
    else {
      int q = (z - 512) >> 8; E = 256;
      cw = (q == 0) ? cw2 : ((q == 1) ? cw3 : cw4);
      wt = (q == 0) ? wt2 : ((q == 1) ? wt3 : wt4);
      z = (z - 512) & 255;
    }
    int NCw = (3 * E) >> 6;
    int idx = z * 256 + tid;              // over F*E
    int f = idx / E, e = idx - f * E;
    const float* s = cw + (size_t)idx * 3;
    int ct = f >> 5, i32 = f & 31;
#pragma unroll
    for (int ks = 0; ks < 3; ++ks) {
      int kcol = ks * E + e;
      int cg = kcol >> 6, kk = (kcol >> 4) & 3, hh = (kcol >> 3) & 1, j = kcol & 7;
      wt[(size_t)((((ct * NCw + cg) * 4 + kk) * 2 + hh) * 32 + i32) * 8 + j] =
          (unsigned short)f2bf(s[ks]);
    }
  } else if (bid < 1304) {                // wab -> frag order, direct coalesced read
    int tw = bid - 1280;                  // 24 tiles: half(2) x dt(6) x nt(2)
    int half = tw / 12, rem = tw % 12, dt = rem >> 1, nt = rem & 1;
    int c = tid & 63, rq = tid >> 6;
    int n = half * 128 + nt * 64 + c;     // A/C column
    int ct = n >> 5, i32 = n & 31;
#pragma unroll
    for (int it = 0; it < 16; ++it) {
      int r2 = rq + it * 4;
      int kp = dt * 64 + r2;              // k index (0..383, use <320)
      if (kp < 320) {
        float v = (kp < 258) ? W1[(size_t)(half * 258 + kp) * 128 + nt * 64 + c] : 0.f;
        int cg = kp >> 6, kk = (kp >> 4) & 3, hh = (kp >> 3) & 1, j = kp & 7;
        wabf[(size_t)((((ct * 5 + cg) * 4 + kk) * 2 + hh) * 32 + i32) * 8 + j] =
            (unsigned short)f2bf(v);
      }
    }
  } else if (bid < 1496) {                // wmlp frag-order, reads coalesced over n
    int i2 = (bid - 1304) * 256 + tid;    // z(3) x k(128) x n(128)
    int n = i2 & 127, k = (i2 >> 7) & 127, zz = i2 >> 14;
    const float* W = (zz == 0) ? W2 : ((zz == 1) ? W3 : W4);
    float v = W[k * 128 + n];
    int w = n >> 5, l = ((k >> 3) & 1) * 32 + (n & 31), kk = k >> 4, j = k & 7;
    int i = (((zz * 4 + w) * 8 + kk) << 9) | (l << 3) | j;
    wmlp[i] = (unsigned short)f2bf(v);
  } else if (bid < 1528) {                // hc direct: 32 blocks, 256 thr = 2 k-halves
    int b = bid - 1496;
    int m = tid & 127, kh = tid >> 7;
    const float* hr = h + b * 512 + kh * 256;
    const float* Wc = W1 + (size_t)(516 + kh * 256) * 128 + m;
    float a0 = 0.f, a1 = 0.f, a2 = 0.f, a3 = 0.f, a4 = 0.f, a5 = 0.f, a6 = 0.f, a7 = 0.f;
#pragma unroll
    for (int k = 0; k < 256; k += 8) {
      a0 += hr[k + 0] * Wc[(size_t)(k + 0) * 128];
      a1 += hr[k + 1] * Wc[(size_t)(k + 1) * 128];
      a2 += hr[k + 2] * Wc[(size_t)(k + 2) * 128];
      a3 += hr[k + 3] * Wc[(size_t)(k + 3) * 128];
      a4 += hr[k + 4] * Wc[(size_t)(k + 4) * 128];
      a5 += hr[k + 5] * Wc[(size_t)(k + 5) * 128];
      a6 += hr[k + 6] * Wc[(size_t)(k + 6) * 128];
      a7 += hr[k + 7] * Wc[(size_t)(k + 7) * 128];
    }
    float s = ((a0 + a1) + (a2 + a3)) + ((a4 + a5) + (a6 + a7));
    tile[tid] = s;
    __syncthreads();
    if (kh == 0) hc[b * 128 + m] = tile[m] + tile[128 + m];
  } else {                                // zero bn0..bn3 + sbuf (floats [0,6144))
    int i = (bid - 1528) * 256 + tid;
    zmem[i] = 0.f;
  }
}

// ---------------- conv: 800 blocks = 100 row-tiles x 8 col-tiles(32f);
// 4 waves = K-quarters, B-frags direct from global (frag-order, L2-resident),
// no barriers in K-loop; LDS = input slab only; combine via LDS scratch.
__global__ __launch_bounds__(256, 4) void k_conv(
    const float* __restrict__ zin, const float* __restrict__ bnin,
    const float* __restrict__ gamv, const float* __restrict__ betv,
    const unsigned short* __restrict__ wtf, const float* __restrict__ cb,
    float* __restrict__ zout, float* __restrict__ bnout, int E, int xmode) {
  extern __shared__ unsigned short smem[];
  const int SL = (E == 512) ? 520 : 264;     // dword-stride % 32 == 4
  unsigned short* slab = smem;               // 34 x SL
  const int NC = (3 * E) >> 6, NCQ = NC >> 2;
  const int esh = (E == 512) ? 9 : 8;
  int tid = threadIdx.x;
  int lane = tid & 63, wave = tid >> 6;      // wave = K-quarter
  int bid = blockIdx.x;
  int r0 = (bid % 100) * 32, ct = bid / 100; // ct 0..7
  int i32 = lane & 31, h = lane >> 5;

  int lrow = (r0 + i32) % 100;
  bool vks0 = (lrow >= 1), vks2 = (lrow <= 98);

  // ---- stage input slab, 4 waves
  if (xmode) {  // conv1: x is (L,B,E) fp32, E=512
    for (int s = wave; s < 34; s += 4) {
      int m = r0 - 1 + s; m = min(max(m, 0), 3199);
      int b = m / 100, l = m - b * 100;
      size_t base = (size_t)(l * 32 + b) * 512;
#pragma unroll
      for (int cc = 0; cc < 2; ++cc) {
        int ch = cc * 256 + lane * 4;
        float4 v = *(const float4*)(zin + base + ch);
        uint2 p; p.x = pk2bf(v.x, v.y); p.y = pk2bf(v.z, v.w);
        *(uint2*)(&slab[s * SL + ch]) = p;
      }
    }
  } else {      // convs 2-4: z (m,256) fp32 with BN applied on stage
    const float inv = 1.f / 3200.f;
    float sc[4], sh[4];
#pragma unroll
    for (int q = 0; q < 4; ++q) {
      int ch = lane * 4 + q;
      float mme = bnin[ch] * inv;
      float var = bnin[256 + ch] * inv - mme * mme;
      sc[q] = gamv[ch] * rsqrtf(var + 1e-5f);
      sh[q] = betv[ch] - mme * sc[q];
    }
    for (int s = wave; s < 34; s += 4) {
      int m = r0 - 1 + s; m = min(max(m, 0), 3199);
      float4 v = *(const float4*)(zin + (size_t)m * 256 + lane * 4);
      uint2 p;
      p.x = pk2bf(v.x * sc[0] + sh[0], v.y * sc[1] + sh[1]);
      p.y = pk2bf(v.z * sc[2] + sh[2], v.w * sc[3] + sh[3]);
      *(uint2*)(&slab[s * SL + lane * 4]) = p;
    }
  }
  __syncthreads();

  floatx16 acc;
#pragma unroll
  for (int q = 0; q < 16; ++q) acc[q] = 0.f;

  int cg0 = wave * NCQ;
  const unsigned short* wp = wtf + (size_t)((ct * NC + cg0) * 8 + h) * 256 + i32 * 8;
  short8 bpre[4];
#pragma unroll
  for (int kk = 0; kk < 4; ++kk) bpre[kk] = *(const short8*)(wp + kk * 512);

  for (int c = 0; c < NCQ; ++c) {
    short8 bcur[4];
#pragma unroll
    for (int kk = 0; kk < 4; ++kk) bcur[kk] = bpre[kk];
    if (c + 1 < NCQ) {
      wp += 2048;
#pragma unroll
      for (int kk = 0; kk < 4; ++kk) bpre[kk] = *(const short8*)(wp + kk * 512);
    }
    int cg = cg0 + c;
    int ks = (cg << 6) >> esh;
    int ebase = (cg << 6) & (E - 1);
    bool v = (ks == 0) ? vks0 : ((ks == 2) ? vks2 : true);
    int srow = i32 + ks;
#pragma unroll
    for (int kk = 0; kk < 4; ++kk) {
      short8 a = {};
      if (v) a = *(const short8*)(&slab[srow * SL + ebase + kk * 16 + h * 8]);
      acc = __builtin_amdgcn_mfma_f32_32x32x16_bf16(a, bcur[kk], acc, 0, 0, 0);
    }
  }

  // ---- combine K-quarters via LDS scratch (reuses slab region)
  __syncthreads();
  float* scr = (float*)smem;                 // 3 x 32 x 32 floats = 12 KB
  if (wave) {
#pragma unroll
    for (int reg = 0; reg < 16; ++reg) {
      int rowp = (reg & 3) + 8 * (reg >> 2) + 4 * h;
      scr[(wave - 1) * 1024 + rowp * 32 + i32] = acc[reg];
    }
  }
  __syncthreads();
  if (wave == 0) {
    int f = ct * 32 + i32;
    float bias = cb[f];
    float s1 = 0.f, s2 = 0.f;
#pragma unroll
    for (int reg = 0; reg < 16; ++reg) {
      int rowp = (reg & 3) + 8 * (reg >> 2) + 4 * h;
      int m = r0 + rowp;
      float v = acc[reg] + scr[rowp * 32 + i32] + scr[1024 + rowp * 32 + i32]
              + scr[2048 + rowp * 32 + i32] + bias;
      v = fmaxf(v, NEG * v);
      zout[(size_t)m * 256 + f] = v;
      s1 += v; s2 += v * v;
    }
    s1 += __shfl_xor(s1, 32, 64);
    s2 += __shfl_xor(s2, 32, 64);
    if (lane < 32) { atomicAdd(&bnout[f], s1); atomicAdd(&bnout[256 + f], s2); }
  }
}

// ---------------- A/C GEMM: 800 blocks = 100 x 8 col-tiles(32n); 4 waves
// K-split over 5 chunks {0,4},{1},{2},{3}; B direct from global; fused BN4+coords.
__global__ __launch_bounds__(256, 4) void k_ac(
    const float* __restrict__ zin, const float* __restrict__ bnin,
    const float* __restrict__ gamv, const float* __restrict__ betv,
    const unsigned short* __restrict__ wabf, const float* __restrict__ hc,
    const float* __restrict__ b1v,
    unsigned short* __restrict__ Abf, unsigned short* __restrict__ Cbf) {
  extern __shared__ unsigned short smem[];
  unsigned short* slab = smem;               // 32 x 328
  int tid = threadIdx.x;
  int lane = tid & 63, wave = tid >> 6;
  int bid = blockIdx.x;
  int r0 = (bid % 100) * 32, ct = bid / 100; // ct 0..7
  int i32 = lane & 31, h = lane >> 5;
  const float inv = 1.f / 3200.f;

  {
    float sc[4], sh[4];
#pragma unroll
    for (int q = 0; q < 4; ++q) {
      int ch = lane * 4 + q;
      float mme = bnin[ch] * inv;
      float var = bnin[256 + ch] * inv - mme * mme;
      sc[q] = gamv[ch] * rsqrtf(var + 1e-5f);
      sh[q] = betv[ch] - mme * sc[q];
    }
    for (int s = wave; s < 32; s += 4) {
      int m = r0 + s;
      float4 v = *(const float4*)(zin + (size_t)m * 256 + lane * 4);
      uint2 p;
      p.x = pk2bf(v.x * sc[0] + sh[0], v.y * sc[1] + sh[1]);
      p.y = pk2bf(v.z * sc[2] + sh[2], v.w * sc[3] + sh[3]);
      *(uint2*)(&slab[s * 328 + lane * 4]) = p;
    }
    if (wave == 0) {   // coords + zero tail, cols 256..319
      int s = i32, half = h * 32;
      int m = r0 + s, l = m % 100;
      float c0 = ((float)l * 0.1f - 2.0f) * 0.5f;
      float c1 = ((float)(l % 10) - 2.0f) * 0.5f;
#pragma unroll
      for (int seg = 0; seg < 4; ++seg) {
        uint4 z4; z4.x = z4.y = z4.z = z4.w = 0u;
        if (half == 0 && seg == 0) z4.x = pk2bf(c0, c1);
        *(uint4*)(&slab[s * 328 + 256 + half + seg * 8]) = z4;
      }
    }
  }
  __syncthreads();

  floatx16 acc;
#pragma unroll
  for (int q = 0; q < 16; ++q) acc[q] = 0.f;

#pragma unroll
  for (int cc = 0; cc < 2; ++cc) {
    int cg = wave + cc * 4;
    if (cg <= 4) {
      const unsigned short* wp = wabf + (size_t)((ct * 5 + cg) * 8 + h) * 256 + i32 * 8;
#pragma unroll
      for (int kk = 0; kk < 4; ++kk) {
        short8 a = *(const short8*)(&slab[i32 * 328 + cg * 64 + kk * 16 + h * 8]);
        short8 b8 = *(const short8*)(wp + kk * 512);
        acc = __builtin_amdgcn_mfma_f32_32x32x16_bf16(a, b8, acc, 0, 0, 0);
      }
    }
  }

  __syncthreads();
  float* scr = (float*)smem;
  if (wave) {
#pragma unroll
    for (int reg = 0; reg < 16; ++reg) {
      int rowp = (reg & 3) + 8 * (reg >> 2) + 4 * h;
      scr[(wave - 1) * 1024 + rowp * 32 + i32] = acc[reg];
    }
  }
  __syncthreads();
  if (wave == 0) {
    int n = ct * 32 + i32;
#pragma unroll
    for (int reg = 0; reg < 16; ++reg) {
      int rowp = (reg & 3) + 8 * (reg >> 2) + 4 * h;
      int m = r0 + rowp;
      float v = acc[reg] + scr[rowp * 32 + i32] + scr[1024 + rowp * 32 + i32]
              + scr[2048 + rowp * 32 + i32];
      if (ct < 4) {
        Abf[(size_t)m * 128 + n] = (unsigned short)f2bf(v);
      } else {
        int b = m / 100;
        int nc = n - 128;
        Cbf[(size_t)m * 128 + nc] =
            (unsigned short)f2bf(v + hc[b * 128 + nc] + b1v[nc]);
      }
    }
  }
}

// ---------------- fused relation MLP: hot loop identical to R7 except
// layer-2 W4 frags read from GLOBAL (L1/L2-resident 32KB table) -> LDS
// drops to 66.5 KB -> 2 blocks/CU; grid 512 -> max 2 units/slot (was 3).
__device__ __forceinline__ void mlp_layer(const int z, const unsigned short* wlds,
                                          const float* bias_lds, const int lane,
                                          const int h, const short8 (&gin)[8],
                                          short8 (&gout)[8]) {
#pragma unroll
  for (int a = 0; a < 4; ++a) {
    floatx16 acc;
#pragma unroll
    for (int q = 0; q < 16; ++q) acc[q] = 0.f;
#pragma unroll
    for (int kk = 0; kk < 8; ++kk) {
      short8 wf = *(const short8*)(wlds + (((z * 4 + a) * 8 + kk) << 9) + lane * 8);
      acc = __builtin_amdgcn_mfma_f32_32x32x16_bf16(wf, gin[kk], acc, 0, 0, 0);
    }
    // bias + lrelu (of = 32a + 8q + 4h + t)
#pragma unroll
    for (int qg = 0; qg < 4; ++qg) {
      float4 bb = *(const float4*)(bias_lds + z * 128 + a * 32 + qg * 8 + h * 4);
      float v0 = acc[qg * 4 + 0] + bb.x;
      float v1 = acc[qg * 4 + 1] + bb.y;
      float v2 = acc[qg * 4 + 2] + bb.z;
      float v3 = acc[qg * 4 + 3] + bb.w;
      acc[qg * 4 + 0] = fmaxf(v0, NEG * v0);
      acc[qg * 4 + 1] = fmaxf(v1, NEG * v1);
      acc[qg * 4 + 2] = fmaxf(v2, NEG * v2);
      acc[qg * 4 + 3] = fmaxf(v3, NEG * v3);
    }
    // pack + half-swap -> B-frags for next layer
#pragma unroll
    for (int c = 0; c < 2; ++c) {
      unsigned X0 = pk2bf(acc[8 * c + 0], acc[8 * c + 1]);
      unsigned X1 = pk2bf(acc[8 * c + 2], acc[8 * c + 3]);
      unsigned Y0 = pk2bf(acc[8 * c + 4], acc[8 * c + 5]);
      unsigned Y1 = pk2bf(acc[8 * c + 6], acc[8 * c + 7]);
      auto p0 = __builtin_amdgcn_permlane32_swap(X0, Y0, false, false);
      auto p1 = __builtin_amdgcn_permlane32_swap(X1, Y1, false, false);
      union { unsigned w[4]; short8 s; } uu;
      uu.w[0] = (unsigned)p0[0]; uu.w[1] = (unsigned)p1[0];
      uu.w[2] = (unsigned)p0[1]; uu.w[3] = (unsigned)p1[1];
      gout[2 * a + c] = uu.s;
    }
  }
}

__global__ __launch_bounds__(1024, 8) void k_mlp(
    const unsigned short* __restrict__ Abf, const unsigned short* __restrict__ Cbf,
    const unsigned short* __restrict__ wmlp, const float* __restrict__ b2,
    const float* __restrict__ b3, const float* __restrict__ b4,
    float* __restrict__ sout) {
  extern __shared__ unsigned short wsm[];        // 32768 shorts W01-frags + 256f bias
  float* bias_lds = (float*)(wsm + 32768);
  int tid = threadIdx.x, lane = tid & 63, wave = tid >> 6;
  int ln31 = lane & 31, h = lane >> 5;

  {  // stage W layers 0-1 frag-order (64 KB) + biases, once per block
    const uint4* s4 = (const uint4*)wmlp;
    uint4* d4 = (uint4*)wsm;
#pragma unroll
    for (int i = 0; i < 4; ++i) d4[tid + i * 1024] = s4[tid + i * 1024];
    if (tid < 256) bias_lds[tid] = (tid < 128) ? b2[tid] : b3[tid - 128];
  }
  float b4v[4];
#pragma unroll
  for (int a = 0; a < 4; ++a) b4v[a] = b4[a * 32 + ln31];
  __syncthreads();   // only barrier in the kernel

  int slot = blockIdx.x * 16 + wave;   // 0..8191 wave-slots
  for (int it = 0; it < 2; ++it) {
    int u = it * 8192 + slot;          // unit = 32 pairs; 313 units per batch
    if (u >= 10016) break;
    int b = u / 313, lu = u - b * 313;
    int r = lu * 32 + ln31;
    int rc = min(r, 9999);
    int i = rc / 100, j = rc - i * 100;
    const unsigned short* Crow = Cbf + (size_t)(b * 100 + i) * 128 + h * 8;
    const unsigned short* Arow = Abf + (size_t)(b * 100 + j) * 128 + h * 8;

    short8 ga[8], gb[8];
    // build g0 = lrelu(C_i + A_j) directly as B-frags (lane=pr, half=k-split)
#pragma unroll
    for (int kk = 0; kk < 8; ++kk) {
      uint4 c4 = *(const uint4*)(Crow + kk * 16);
      uint4 a4 = *(const uint4*)(Arow + kk * 16);
      unsigned cw[4] = {c4.x, c4.y, c4.z, c4.w};
      unsigned aw[4] = {a4.x, a4.y, a4.z, a4.w};
      unsigned ow[4];
#pragma unroll
      for (int q = 0; q < 4; ++q) {
        float x0 = bits2f(cw[q] << 16) + bits2f(aw[q] << 16);
        float x1 = bits2f(cw[q] & 0xFFFF0000u) + bits2f(aw[q] & 0xFFFF0000u);
        x0 = fmaxf(x0, NEG * x0);
        x1 = fmaxf(x1, NEG * x1);
        ow[q] = pk2bf(x0, x1);
      }
      union { unsigned w[4]; short8 s; } uu;
      uu.w[0] = ow[0]; uu.w[1] = ow[1]; uu.w[2] = ow[2]; uu.w[3] = ow[3];
      ga[kk] = uu.s;
    }

    mlp_layer(0, wsm, bias_lds, lane, h, ga, gb);   // g1 = lrelu(g0@W2+b2)
    mlp_layer(1, wsm, bias_lds, lane, h, gb, ga);   // g2 = lrelu(g1@W3+b3)

    // layer 2 unflipped: D[pr][of] = g2 @ W4; W4 frags from global (L1-hot)
#pragma unroll
    for (int a = 0; a < 4; ++a) {
      floatx16 acc;
#pragma unroll
      for (int q = 0; q < 16; ++q) acc[q] = 0.f;
#pragma unroll
      for (int kk = 0; kk < 8; ++kk) {
        short8 wf = *(const short8*)(wmlp + (((8 + a) * 8 + kk) << 9) + lane * 8);
        acc = __builtin_amdgcn_mfma_f32_32x32x16_bf16(ga[kk], wf, acc, 0, 0, 0);
      }
      float s = 0.f;
#pragma unroll
      for (int reg = 0; reg < 16; ++reg) {
        int rowp = (reg & 3) + 8 * (reg >> 2) + 4 * h;
        float v = acc[reg] + b4v[a];
        v = fmaxf(v, NEG * v);
        s += (lu * 32 + rowp < 10000) ? v : 0.f;
      }
      s += __shfl_xor(s, 32, 64);
      if (lane < 32) atomicAdd(&sout[b * 128 + a * 32 + ln31], s);
    }
  }
}

// ---------------- final: out = lrelu(lrelu(s@F1+fb1)@F2+fb2), one block per b
__global__ void k_final(const float* __restrict__ s, const float* __restrict__ F1,
                        const float* __restrict__ fb1, const float* __restrict__ F2,
                        const float* __restrict__ fb2, float* __restrict__ out) {
  __shared__ float sl[128], t1[128];
  int b = blockIdx.x, t = threadIdx.x;
  if (t < 128) sl[t] = s[b * 128 + t];
  __syncthreads();
  if (t < 128) {
    float a = fb1[t];
    for (int k = 0; k < 128; ++k) a += sl[k] * F1[k * 128 + t];
    t1[t] = fmaxf(a, NEG * a);
  }
  __syncthreads();
  for (int o = t; o < 512; o += 256) {
    float a = fb2[o];
    for (int k = 0; k < 128; ++k) a += t1[k] * F2[k * 512 + o];
    out[b * 512 + o] = fmaxf(a, NEG * a);
  }
}

extern "C" void kernel_launch(void* const* d_in, const int* in_sizes, int n_in,
                              void* d_out, int out_size, void* d_ws, size_t ws_size,
                              hipStream_t stream) {
  const float* x   = (const float*)d_in[0];
  const float* h   = (const float*)d_in[1];
  const float* cw1 = (const float*)d_in[2];
  const float* cb1 = (const float*)d_in[3];
  const float* g1  = (const float*)d_in[4];
  const float* be1 = (const float*)d_in[5];
  const float* cw2 = (const float*)d_in[6];
  const float* cb2 = (const float*)d_in[7];
  const float* g2  = (const float*)d_in[8];
  const float* be2 = (const float*)d_in[9];
  const float* cw3 = (const float*)d_in[10];
  const float* cb3 = (const float*)d_in[11];
  const float* g3  = (const float*)d_in[12];
  const float* be3 = (const float*)d_in[13];
  const float* cw4 = (const float*)d_in[14];
  const float* cb4 = (const float*)d_in[15];
  const float* g4  = (const float*)d_in[16];
  const float* be4 = (const float*)d_in[17];
  const float* W1  = (const float*)d_in[18];
  const float* b1  = (const float*)d_in[19];
  const float* W2  = (const float*)d_in[20];
  const float* b2  = (const float*)d_in[21];
  const float* W3  = (const float*)d_in[22];
  const float* b3  = (const float*)d_in[23];
  const float* W4  = (const float*)d_in[24];
  const float* b4  = (const float*)d_in[25];
  const float* F1  = (const float*)d_in[26];
  const float* fb1 = (const float*)d_in[27];
  const float* F2  = (const float*)d_in[28];
  const float* fb2 = (const float*)d_in[29];

  char* ws = (char*)d_ws;
  float* zmem = (float*)(ws + 0);                           // zero region
  float* bn0  = (float*)(ws + 0);
  float* bn1  = (float*)(ws + 2048);
  float* bn2  = (float*)(ws + 4096);
  float* bn3  = (float*)(ws + 6144);
  float* sbuf = (float*)(ws + 8192);                        // 32x128 fp32
  float* hc   = (float*)(ws + 24576);                       // 32x128 fp32 (direct-written)
  float* za   = (float*)(ws + 40960);                       // 3200x256 fp32
  float* zb   = (float*)(ws + 3317760);                     // 3200x256 fp32
  unsigned short* wt1  = (unsigned short*)(ws + 6594560);   // frag-order 786KB
  unsigned short* wt2  = (unsigned short*)(ws + 7380992);   // frag-order 384KB
  unsigned short* wt3  = (unsigned short*)(ws + 7774208);
  unsigned short* wt4  = (unsigned short*)(ws + 8167424);
  unsigned short* wabf = (unsigned short*)(ws + 8560640);   // frag-order 160KB
  unsigned short* wmlp = (unsigned short*)(ws + 8757248);   // 3x16384 frag-order
  unsigned short* Abf  = (unsigned short*)(ws + 8855552);   // 3200x128 bf16
  unsigned short* Cbf  = (unsigned short*)(ws + 9674752);   // 3200x128 bf16; end 10493952

  k_prep<<<1552, 256, 0, stream>>>(cw1, cw2, cw3, cw4, wt1, wt2, wt3, wt4,
                                   W1, wabf, W2, W3, W4, wmlp, h, hc, zmem);

  const int lds1 = 34 * 520 * 2;   // 35360 B
  const int lds2 = 34 * 264 * 2;   // 17952 B
  k_conv<<<800, 256, lds1, stream>>>(x,  nullptr, nullptr, nullptr, wt1, cb1, za, bn0, 512, 1);
  k_conv<<<800, 256, lds2, stream>>>(za, bn0, g1, be1, wt2, cb2, zb, bn1, 256, 0);
  k_conv<<<800, 256, lds2, stream>>>(zb, bn1, g2, be2, wt3, cb3, za, bn2, 256, 0);
  k_conv<<<800, 256, lds2, stream>>>(za, bn2, g3, be3, wt4, cb4, zb, bn3, 256, 0);

  const int ldsa = 32 * 328 * 2;   // 20992 B
  k_ac<<<800, 256, ldsa, stream>>>(zb, bn3, g4, be4, wabf, hc, b1, Abf, Cbf);

  const int ldsm = 32768 * 2 + 256 * 4;            // 66560 B: W01 frags + b2/b3
  k_mlp<<<512, 1024, ldsm, stream>>>(Abf, Cbf, wmlp, b2, b3, b4, sbuf);
  k_final<<<32, 256, 0, stream>>>(sbuf, F1, fb1, F2, fb2, (float*)d_out);
}

// Round 13
// 239.554 us; speedup vs baseline: 1.5587x; 1.5587x over previous
//
#include <hip/hip_runtime.h>
#include <hip/hip_bf16.h>
#include <stdint.h>
#include <stddef.h>

#define NEG 0.1f

typedef __attribute__((ext_vector_type(8))) short short8;
typedef __attribute__((ext_vector_type(16))) float floatx16;

__device__ __forceinline__ unsigned f2bf(float f) {
  union { float f; unsigned u; } v; v.f = f;
  unsigned r = v.u + 0x7FFFu + ((v.u >> 16) & 1u);   // RNE
  return r >> 16;
}
__device__ __forceinline__ unsigned pk2bf(float a, float b) {   // a->low16, b->high16
  __hip_bfloat162 hh = __float22bfloat162_rn(make_float2(a, b));
  union { __hip_bfloat162 h; unsigned u; } v; v.h = hh; return v.u;
}
__device__ __forceinline__ float bits2f(unsigned u) {
  union { unsigned u; float f; } v; v.u = u; return v.f;
}

// frag-order index for B-operand tiles: element (row f = ct*32+i32,
// col kcol = cg*64 + kk*16 + h*8 + j) ->
//   (((ct*NC + cg)*4 + kk)*2 + h)*256 + i32*8 + j

// ---------------- fused prep: conv-w frag-order | wab frag-order | wmlp |
//                  hc (direct) | ws zero
__global__ void k_prep(const float* __restrict__ cw1, const float* __restrict__ cw2,
                       const float* __restrict__ cw3, const float* __restrict__ cw4,
                       unsigned short* __restrict__ wt1, unsigned short* __restrict__ wt2,
                       unsigned short* __restrict__ wt3, unsigned short* __restrict__ wt4,
                       const float* __restrict__ W1, unsigned short* __restrict__ wabf,
                       const float* __restrict__ W2, const float* __restrict__ W3,
                       const float* __restrict__ W4, unsigned short* __restrict__ wmlp,
                       const float* __restrict__ h, float* __restrict__ hc,
                       float* __restrict__ zmem) {
  __shared__ float tile[256];
  int bid = blockIdx.x, tid = threadIdx.x;
  if (bid < 1280) {                       // conv weights -> frag order
    int z = bid;
    int E; const float* cw; unsigned short* wt;
    if (z < 512) { E = 512; cw = cw1; wt = wt1; }
    else {
      int q = (z - 512) >> 8; E = 256;
      cw = (q == 0) ? cw2 : ((q == 1) ? cw3 : cw4);
      wt = (q == 0) ? wt2 : ((q == 1) ? wt3 : wt4);
      z = (z - 512) & 255;
    }
    int NCw = (3 * E) >> 6;
    int idx = z * 256 + tid;              // over F*E
    int f = idx / E, e = idx - f * E;
    const float* s = cw + (size_t)idx * 3;
    int ct = f >> 5, i32 = f & 31;
#pragma unroll
    for (int ks = 0; ks < 3; ++ks) {
      int kcol = ks * E + e;
      int cg = kcol >> 6, kk = (kcol >> 4) & 3, hh = (kcol >> 3) & 1, j = kcol & 7;
      wt[(size_t)((((ct * NCw + cg) * 4 + kk) * 2 + hh) * 32 + i32) * 8 + j] =
          (unsigned short)f2bf(s[ks]);
    }
  } else if (bid < 1304) {                // wab -> frag order, direct coalesced read
    int tw = bid - 1280;                  // 24 tiles: half(2) x dt(6) x nt(2)
    int half = tw / 12, rem = tw % 12, dt = rem >> 1, nt = rem & 1;
    int c = tid & 63, rq = tid >> 6;
    int n = half * 128 + nt * 64 + c;     // A/C column
    int ct = n >> 5, i32 = n & 31;
#pragma unroll
    for (int it = 0; it < 16; ++it) {
      int r2 = rq + it * 4;
      int kp = dt * 64 + r2;              // k index (0..383, use <320)
      if (kp < 320) {
        float v = (kp < 258) ? W1[(size_t)(half * 258 + kp) * 128 + nt * 64 + c] : 0.f;
        int cg = kp >> 6, kk = (kp >> 4) & 3, hh = (kp >> 3) & 1, j = kp & 7;
        wabf[(size_t)((((ct * 5 + cg) * 4 + kk) * 2 + hh) * 32 + i32) * 8 + j] =
            (unsigned short)f2bf(v);
      }
    }
  } else if (bid < 1496) {                // wmlp frag-order, reads coalesced over n
    int i2 = (bid - 1304) * 256 + tid;    // z(3) x k(128) x n(128)
    int n = i2 & 127, k = (i2 >> 7) & 127, zz = i2 >> 14;
    const float* W = (zz == 0) ? W2 : ((zz == 1) ? W3 : W4);
    float v = W[k * 128 + n];
    int w = n >> 5, l = ((k >> 3) & 1) * 32 + (n & 31), kk = k >> 4, j = k & 7;
    int i = (((zz * 4 + w) * 8 + kk) << 9) | (l << 3) | j;
    wmlp[i] = (unsigned short)f2bf(v);
  } else if (bid < 1528) {                // hc direct: 32 blocks, 256 thr = 2 k-halves
    int b = bid - 1496;
    int m = tid & 127, kh = tid >> 7;
    const float* hr = h + b * 512 + kh * 256;
    const float* Wc = W1 + (size_t)(516 + kh * 256) * 128 + m;
    float a0 = 0.f, a1 = 0.f, a2 = 0.f, a3 = 0.f, a4 = 0.f, a5 = 0.f, a6 = 0.f, a7 = 0.f;
#pragma unroll
    for (int k = 0; k < 256; k += 8) {
      a0 += hr[k + 0] * Wc[(size_t)(k + 0) * 128];
      a1 += hr[k + 1] * Wc[(size_t)(k + 1) * 128];
      a2 += hr[k + 2] * Wc[(size_t)(k + 2) * 128];
      a3 += hr[k + 3] * Wc[(size_t)(k + 3) * 128];
      a4 += hr[k + 4] * Wc[(size_t)(k + 4) * 128];
      a5 += hr[k + 5] * Wc[(size_t)(k + 5) * 128];
      a6 += hr[k + 6] * Wc[(size_t)(k + 6) * 128];
      a7 += hr[k + 7] * Wc[(size_t)(k + 7) * 128];
    }
    float s = ((a0 + a1) + (a2 + a3)) + ((a4 + a5) + (a6 + a7));
    tile[tid] = s;
    __syncthreads();
    if (kh == 0) hc[b * 128 + m] = tile[m] + tile[128 + m];
  } else {                                // zero bn0..bn3 + sbuf (floats [0,6144))
    int i = (bid - 1528) * 256 + tid;
    zmem[i] = 0.f;
  }
}

// ---------------- conv: 800 blocks = 100 row-tiles x 8 col-tiles(32f);
// 4 waves = K-quarters, B-frags direct from global (frag-order, L2-resident),
// no barriers in K-loop; LDS = input slab only; combine via LDS scratch.
__global__ __launch_bounds__(256, 4) void k_conv(
    const float* __restrict__ zin, const float* __restrict__ bnin,
    const float* __restrict__ gamv, const float* __restrict__ betv,
    const unsigned short* __restrict__ wtf, const float* __restrict__ cb,
    float* __restrict__ zout, float* __restrict__ bnout, int E, int xmode) {
  extern __shared__ unsigned short smem[];
  const int SL = (E == 512) ? 520 : 264;     // dword-stride % 32 == 4
  unsigned short* slab = smem;               // 34 x SL
  const int NC = (3 * E) >> 6, NCQ = NC >> 2;
  const int esh = (E == 512) ? 9 : 8;
  int tid = threadIdx.x;
  int lane = tid & 63, wave = tid >> 6;      // wave = K-quarter
  int bid = blockIdx.x;
  int r0 = (bid % 100) * 32, ct = bid / 100; // ct 0..7
  int i32 = lane & 31, h = lane >> 5;

  int lrow = (r0 + i32) % 100;
  bool vks0 = (lrow >= 1), vks2 = (lrow <= 98);

  // ---- stage input slab, 4 waves
  if (xmode) {  // conv1: x is (L,B,E) fp32, E=512
    for (int s = wave; s < 34; s += 4) {
      int m = r0 - 1 + s; m = min(max(m, 0), 3199);
      int b = m / 100, l = m - b * 100;
      size_t base = (size_t)(l * 32 + b) * 512;
#pragma unroll
      for (int cc = 0; cc < 2; ++cc) {
        int ch = cc * 256 + lane * 4;
        float4 v = *(const float4*)(zin + base + ch);
        uint2 p; p.x = pk2bf(v.x, v.y); p.y = pk2bf(v.z, v.w);
        *(uint2*)(&slab[s * SL + ch]) = p;
      }
    }
  } else {      // convs 2-4: z (m,256) fp32 with BN applied on stage
    const float inv = 1.f / 3200.f;
    float sc[4], sh[4];
#pragma unroll
    for (int q = 0; q < 4; ++q) {
      int ch = lane * 4 + q;
      float mme = bnin[ch] * inv;
      float var = bnin[256 + ch] * inv - mme * mme;
      sc[q] = gamv[ch] * rsqrtf(var + 1e-5f);
      sh[q] = betv[ch] - mme * sc[q];
    }
    for (int s = wave; s < 34; s += 4) {
      int m = r0 - 1 + s; m = min(max(m, 0), 3199);
      float4 v = *(const float4*)(zin + (size_t)m * 256 + lane * 4);
      uint2 p;
      p.x = pk2bf(v.x * sc[0] + sh[0], v.y * sc[1] + sh[1]);
      p.y = pk2bf(v.z * sc[2] + sh[2], v.w * sc[3] + sh[3]);
      *(uint2*)(&slab[s * SL + lane * 4]) = p;
    }
  }
  __syncthreads();

  floatx16 acc;
#pragma unroll
  for (int q = 0; q < 16; ++q) acc[q] = 0.f;

  int cg0 = wave * NCQ;
  const unsigned short* wp = wtf + (size_t)((ct * NC + cg0) * 8 + h) * 256 + i32 * 8;
  short8 bpre[4];
#pragma unroll
  for (int kk = 0; kk < 4; ++kk) bpre[kk] = *(const short8*)(wp + kk * 512);

  for (int c = 0; c < NCQ; ++c) {
    short8 bcur[4];
#pragma unroll
    for (int kk = 0; kk < 4; ++kk) bcur[kk] = bpre[kk];
    if (c + 1 < NCQ) {
      wp += 2048;
#pragma unroll
      for (int kk = 0; kk < 4; ++kk) bpre[kk] = *(const short8*)(wp + kk * 512);
    }
    int cg = cg0 + c;
    int ks = (cg << 6) >> esh;
    int ebase = (cg << 6) & (E - 1);
    bool v = (ks == 0) ? vks0 : ((ks == 2) ? vks2 : true);
    int srow = i32 + ks;
#pragma unroll
    for (int kk = 0; kk < 4; ++kk) {
      short8 a = {};
      if (v) a = *(const short8*)(&slab[srow * SL + ebase + kk * 16 + h * 8]);
      acc = __builtin_amdgcn_mfma_f32_32x32x16_bf16(a, bcur[kk], acc, 0, 0, 0);
    }
  }

  // ---- combine K-quarters via LDS scratch (reuses slab region)
  __syncthreads();
  float* scr = (float*)smem;                 // 3 x 32 x 32 floats = 12 KB
  if (wave) {
#pragma unroll
    for (int reg = 0; reg < 16; ++reg) {
      int rowp = (reg & 3) + 8 * (reg >> 2) + 4 * h;
      scr[(wave - 1) * 1024 + rowp * 32 + i32] = acc[reg];
    }
  }
  __syncthreads();
  if (wave == 0) {
    int f = ct * 32 + i32;
    float bias = cb[f];
    float s1 = 0.f, s2 = 0.f;
#pragma unroll
    for (int reg = 0; reg < 16; ++reg) {
      int rowp = (reg & 3) + 8 * (reg >> 2) + 4 * h;
      int m = r0 + rowp;
      float v = acc[reg] + scr[rowp * 32 + i32] + scr[1024 + rowp * 32 + i32]
              + scr[2048 + rowp * 32 + i32] + bias;
      v = fmaxf(v, NEG * v);
      zout[(size_t)m * 256 + f] = v;
      s1 += v; s2 += v * v;
    }
    s1 += __shfl_xor(s1, 32, 64);
    s2 += __shfl_xor(s2, 32, 64);
    if (lane < 32) { atomicAdd(&bnout[f], s1); atomicAdd(&bnout[256 + f], s2); }
  }
}

// ---------------- A/C GEMM: 800 blocks = 100 x 8 col-tiles(32n); 4 waves
// K-split over 5 chunks {0,4},{1},{2},{3}; B direct from global; fused BN4+coords.
__global__ __launch_bounds__(256, 4) void k_ac(
    const float* __restrict__ zin, const float* __restrict__ bnin,
    const float* __restrict__ gamv, const float* __restrict__ betv,
    const unsigned short* __restrict__ wabf, const float* __restrict__ hc,
    const float* __restrict__ b1v,
    unsigned short* __restrict__ Abf, unsigned short* __restrict__ Cbf) {
  extern __shared__ unsigned short smem[];
  unsigned short* slab = smem;               // 32 x 328
  int tid = threadIdx.x;
  int lane = tid & 63, wave = tid >> 6;
  int bid = blockIdx.x;
  int r0 = (bid % 100) * 32, ct = bid / 100; // ct 0..7
  int i32 = lane & 31, h = lane >> 5;
  const float inv = 1.f / 3200.f;

  {
    float sc[4], sh[4];
#pragma unroll
    for (int q = 0; q < 4; ++q) {
      int ch = lane * 4 + q;
      float mme = bnin[ch] * inv;
      float var = bnin[256 + ch] * inv - mme * mme;
      sc[q] = gamv[ch] * rsqrtf(var + 1e-5f);
      sh[q] = betv[ch] - mme * sc[q];
    }
    for (int s = wave; s < 32; s += 4) {
      int m = r0 + s;
      float4 v = *(const float4*)(zin + (size_t)m * 256 + lane * 4);
      uint2 p;
      p.x = pk2bf(v.x * sc[0] + sh[0], v.y * sc[1] + sh[1]);
      p.y = pk2bf(v.z * sc[2] + sh[2], v.w * sc[3] + sh[3]);
      *(uint2*)(&slab[s * 328 + lane * 4]) = p;
    }
    if (wave == 0) {   // coords + zero tail, cols 256..319
      int s = i32, half = h * 32;
      int m = r0 + s, l = m % 100;
      float c0 = ((float)l * 0.1f - 2.0f) * 0.5f;
      float c1 = ((float)(l % 10) - 2.0f) * 0.5f;
#pragma unroll
      for (int seg = 0; seg < 4; ++seg) {
        uint4 z4; z4.x = z4.y = z4.z = z4.w = 0u;
        if (half == 0 && seg == 0) z4.x = pk2bf(c0, c1);
        *(uint4*)(&slab[s * 328 + 256 + half + seg * 8]) = z4;
      }
    }
  }
  __syncthreads();

  floatx16 acc;
#pragma unroll
  for (int q = 0; q < 16; ++q) acc[q] = 0.f;

#pragma unroll
  for (int cc = 0; cc < 2; ++cc) {
    int cg = wave + cc * 4;
    if (cg <= 4) {
      const unsigned short* wp = wabf + (size_t)((ct * 5 + cg) * 8 + h) * 256 + i32 * 8;
#pragma unroll
      for (int kk = 0; kk < 4; ++kk) {
        short8 a = *(const short8*)(&slab[i32 * 328 + cg * 64 + kk * 16 + h * 8]);
        short8 b8 = *(const short8*)(wp + kk * 512);
        acc = __builtin_amdgcn_mfma_f32_32x32x16_bf16(a, b8, acc, 0, 0, 0);
      }
    }
  }

  __syncthreads();
  float* scr = (float*)smem;
  if (wave) {
#pragma unroll
    for (int reg = 0; reg < 16; ++reg) {
      int rowp = (reg & 3) + 8 * (reg >> 2) + 4 * h;
      scr[(wave - 1) * 1024 + rowp * 32 + i32] = acc[reg];
    }
  }
  __syncthreads();
  if (wave == 0) {
    int n = ct * 32 + i32;
#pragma unroll
    for (int reg = 0; reg < 16; ++reg) {
      int rowp = (reg & 3) + 8 * (reg >> 2) + 4 * h;
      int m = r0 + rowp;
      float v = acc[reg] + scr[rowp * 32 + i32] + scr[1024 + rowp * 32 + i32]
              + scr[2048 + rowp * 32 + i32];
      if (ct < 4) {
        Abf[(size_t)m * 128 + n] = (unsigned short)f2bf(v);
      } else {
        int b = m / 100;
        int nc = n - 128;
        Cbf[(size_t)m * 128 + nc] =
            (unsigned short)f2bf(v + hc[b * 128 + nc] + b1v[nc]);
      }
    }
  }
}

// ---------------- fused relation MLP (R1/R7-proven version): barrier-free,
// g register-resident; W frags from LDS (96 KB, staged once).
__device__ __forceinline__ void mlp_layer(const int z, const unsigned short* wlds,
                                          const float* bias_lds, const int lane,
                                          const int h, const short8 (&gin)[8],
                                          short8 (&gout)[8]) {
#pragma unroll
  for (int a = 0; a < 4; ++a) {
    floatx16 acc;
#pragma unroll
    for (int q = 0; q < 16; ++q) acc[q] = 0.f;
#pragma unroll
    for (int kk = 0; kk < 8; ++kk) {
      short8 wf = *(const short8*)(wlds + (((z * 4 + a) * 8 + kk) << 9) + lane * 8);
      acc = __builtin_amdgcn_mfma_f32_32x32x16_bf16(wf, gin[kk], acc, 0, 0, 0);
    }
    // bias + lrelu (of = 32a + 8q + 4h + t)
#pragma unroll
    for (int qg = 0; qg < 4; ++qg) {
      float4 bb = *(const float4*)(bias_lds + z * 128 + a * 32 + qg * 8 + h * 4);
      float v0 = acc[qg * 4 + 0] + bb.x;
      float v1 = acc[qg * 4 + 1] + bb.y;
      float v2 = acc[qg * 4 + 2] + bb.z;
      float v3 = acc[qg * 4 + 3] + bb.w;
      acc[qg * 4 + 0] = fmaxf(v0, NEG * v0);
      acc[qg * 4 + 1] = fmaxf(v1, NEG * v1);
      acc[qg * 4 + 2] = fmaxf(v2, NEG * v2);
      acc[qg * 4 + 3] = fmaxf(v3, NEG * v3);
    }
    // pack + half-swap -> B-frags for next layer
#pragma unroll
    for (int c = 0; c < 2; ++c) {
      unsigned X0 = pk2bf(acc[8 * c + 0], acc[8 * c + 1]);
      unsigned X1 = pk2bf(acc[8 * c + 2], acc[8 * c + 3]);
      unsigned Y0 = pk2bf(acc[8 * c + 4], acc[8 * c + 5]);
      unsigned Y1 = pk2bf(acc[8 * c + 6], acc[8 * c + 7]);
      auto p0 = __builtin_amdgcn_permlane32_swap(X0, Y0, false, false);
      auto p1 = __builtin_amdgcn_permlane32_swap(X1, Y1, false, false);
      union { unsigned w[4]; short8 s; } uu;
      uu.w[0] = (unsigned)p0[0]; uu.w[1] = (unsigned)p1[0];
      uu.w[2] = (unsigned)p0[1]; uu.w[3] = (unsigned)p1[1];
      gout[2 * a + c] = uu.s;
    }
  }
}

__global__ __launch_bounds__(1024, 4) void k_mlp(
    const unsigned short* __restrict__ Abf, const unsigned short* __restrict__ Cbf,
    const unsigned short* __restrict__ wmlp, const float* __restrict__ b2,
    const float* __restrict__ b3, const float* __restrict__ b4,
    float* __restrict__ sout) {
  extern __shared__ unsigned short wsm[];        // 49152 shorts W-frags + 256 floats bias
  float* bias_lds = (float*)(wsm + 49152);
  int tid = threadIdx.x, lane = tid & 63, wave = tid >> 6;
  int ln31 = lane & 31, h = lane >> 5;

  {  // stage W frag-order (96 KB) + biases, once per block
    const uint4* s4 = (const uint4*)wmlp;
    uint4* d4 = (uint4*)wsm;
#pragma unroll
    for (int i = 0; i < 6; ++i) d4[tid + i * 1024] = s4[tid + i * 1024];
    if (tid < 256) bias_lds[tid] = (tid < 128) ? b2[tid] : b3[tid - 128];
  }
  float b4v[4];
#pragma unroll
  for (int a = 0; a < 4; ++a) b4v[a] = b4[a * 32 + ln31];
  __syncthreads();   // only barrier in the kernel

  int slot = blockIdx.x * 16 + wave;   // 0..4095 wave-slots
  for (int it = 0; it < 3; ++it) {
    int u = it * 4096 + slot;          // unit = 32 pairs; 313 units per batch
    if (u >= 10016) break;
    int b = u / 313, lu = u - b * 313;
    int r = lu * 32 + ln31;
    int rc = min(r, 9999);
    int i = rc / 100, j = rc - i * 100;
    const unsigned short* Crow = Cbf + (size_t)(b * 100 + i) * 128 + h * 8;
    const unsigned short* Arow = Abf + (size_t)(b * 100 + j) * 128 + h * 8;

    short8 ga[8], gb[8];
    // build g0 = lrelu(C_i + A_j) directly as B-frags (lane=pr, half=k-split)
#pragma unroll
    for (int kk = 0; kk < 8; ++kk) {
      uint4 c4 = *(const uint4*)(Crow + kk * 16);
      uint4 a4 = *(const uint4*)(Arow + kk * 16);
      unsigned cw[4] = {c4.x, c4.y, c4.z, c4.w};
      unsigned aw[4] = {a4.x, a4.y, a4.z, a4.w};
      unsigned ow[4];
#pragma unroll
      for (int q = 0; q < 4; ++q) {
        float x0 = bits2f(cw[q] << 16) + bits2f(aw[q] << 16);
        float x1 = bits2f(cw[q] & 0xFFFF0000u) + bits2f(aw[q] & 0xFFFF0000u);
        x0 = fmaxf(x0, NEG * x0);
        x1 = fmaxf(x1, NEG * x1);
        ow[q] = pk2bf(x0, x1);
      }
      union { unsigned w[4]; short8 s; } uu;
      uu.w[0] = ow[0]; uu.w[1] = ow[1]; uu.w[2] = ow[2]; uu.w[3] = ow[3];
      ga[kk] = uu.s;
    }

    mlp_layer(0, wsm, bias_lds, lane, h, ga, gb);   // g1 = lrelu(g0@W2+b2)
    mlp_layer(1, wsm, bias_lds, lane, h, gb, ga);   // g2 = lrelu(g1@W3+b3)

    // layer 2 unflipped: D[pr][of] = g2 @ W4; lane = of, regs = pr -> colsum
#pragma unroll
    for (int a = 0; a < 4; ++a) {
      floatx16 acc;
#pragma unroll
      for (int q = 0; q < 16; ++q) acc[q] = 0.f;
#pragma unroll
      for (int kk = 0; kk < 8; ++kk) {
        short8 wf = *(const short8*)(wsm + (((8 + a) * 8 + kk) << 9) + lane * 8);
        acc = __builtin_amdgcn_mfma_f32_32x32x16_bf16(ga[kk], wf, acc, 0, 0, 0);
      }
      float s = 0.f;
#pragma unroll
      for (int reg = 0; reg < 16; ++reg) {
        int rowp = (reg & 3) + 8 * (reg >> 2) + 4 * h;
        float v = acc[reg] + b4v[a];
        v = fmaxf(v, NEG * v);
        s += (lu * 32 + rowp < 10000) ? v : 0.f;
      }
      s += __shfl_xor(s, 32, 64);
      if (lane < 32) atomicAdd(&sout[b * 128 + a * 32 + ln31], s);
    }
  }
}

// ---------------- final: out = lrelu(lrelu(s@F1+fb1)@F2+fb2), one block per b
__global__ void k_final(const float* __restrict__ s, const float* __restrict__ F1,
                        const float* __restrict__ fb1, const float* __restrict__ F2,
                        const float* __restrict__ fb2, float* __restrict__ out) {
  __shared__ float sl[128], t1[128];
  int b = blockIdx.x, t = threadIdx.x;
  if (t < 128) sl[t] = s[b * 128 + t];
  __syncthreads();
  if (t < 128) {
    float a = fb1[t];
    for (int k = 0; k < 128; ++k) a += sl[k] * F1[k * 128 + t];
    t1[t] = fmaxf(a, NEG * a);
  }
  __syncthreads();
  for (int o = t; o < 512; o += 256) {
    float a = fb2[o];
    for (int k = 0; k < 128; ++k) a += t1[k] * F2[k * 512 + o];
    out[b * 512 + o] = fmaxf(a, NEG * a);
  }
}

extern "C" void kernel_launch(void* const* d_in, const int* in_sizes, int n_in,
                              void* d_out, int out_size, void* d_ws, size_t ws_size,
                              hipStream_t stream) {
  const float* x   = (const float*)d_in[0];
  const float* h   = (const float*)d_in[1];
  const float* cw1 = (const float*)d_in[2];
  const float* cb1 = (const float*)d_in[3];
  const float* g1  = (const float*)d_in[4];
  const float* be1 = (const float*)d_in[5];
  const float* cw2 = (const float*)d_in[6];
  const float* cb2 = (const float*)d_in[7];
  const float* g2  = (const float*)d_in[8];
  const float* be2 = (const float*)d_in[9];
  const float* cw3 = (const float*)d_in[10];
  const float* cb3 = (const float*)d_in[11];
  const float* g3  = (const float*)d_in[12];
  const float* be3 = (const float*)d_in[13];
  const float* cw4 = (const float*)d_in[14];
  const float* cb4 = (const float*)d_in[15];
  const float* g4  = (const float*)d_in[16];
  const float* be4 = (const float*)d_in[17];
  const float* W1  = (const float*)d_in[18];
  const float* b1  = (const float*)d_in[19];
  const float* W2  = (const float*)d_in[20];
  const float* b2  = (const float*)d_in[21];
  const float* W3  = (const float*)d_in[22];
  const float* b3  = (const float*)d_in[23];
  const float* W4  = (const float*)d_in[24];
  const float* b4  = (const float*)d_in[25];
  const float* F1  = (const float*)d_in[26];
  const float* fb1 = (const float*)d_in[27];
  const float* F2  = (const float*)d_in[28];
  const float* fb2 = (const float*)d_in[29];

  char* ws = (char*)d_ws;
  float* zmem = (float*)(ws + 0);                           // zero region
  float* bn0  = (float*)(ws + 0);
  float* bn1  = (float*)(ws + 2048);
  float* bn2  = (float*)(ws + 4096);
  float* bn3  = (float*)(ws + 6144);
  float* sbuf = (float*)(ws + 8192);                        // 32x128 fp32
  float* hc   = (float*)(ws + 24576);                       // 32x128 fp32 (direct-written)
  float* za   = (float*)(ws + 40960);                       // 3200x256 fp32
  float* zb   = (float*)(ws + 3317760);                     // 3200x256 fp32
  unsigned short* wt1  = (unsigned short*)(ws + 6594560);   // frag-order 786KB
  unsigned short* wt2  = (unsigned short*)(ws + 7380992);   // frag-order 384KB
  unsigned short* wt3  = (unsigned short*)(ws + 7774208);
  unsigned short* wt4  = (unsigned short*)(ws + 8167424);
  unsigned short* wabf = (unsigned short*)(ws + 8560640);   // frag-order 160KB
  unsigned short* wmlp = (unsigned short*)(ws + 8757248);   // 3x16384 frag-order
  unsigned short* Abf  = (unsigned short*)(ws + 8855552);   // 3200x128 bf16
  unsigned short* Cbf  = (unsigned short*)(ws + 9674752);   // 3200x128 bf16; end 10493952

  k_prep<<<1552, 256, 0, stream>>>(cw1, cw2, cw3, cw4, wt1, wt2, wt3, wt4,
                                   W1, wabf, W2, W3, W4, wmlp, h, hc, zmem);

  const int lds1 = 34 * 520 * 2;   // 35360 B
  const int lds2 = 34 * 264 * 2;   // 17952 B
  k_conv<<<800, 256, lds1, stream>>>(x,  nullptr, nullptr, nullptr, wt1, cb1, za, bn0, 512, 1);
  k_conv<<<800, 256, lds2, stream>>>(za, bn0, g1, be1, wt2, cb2, zb, bn1, 256, 0);
  k_conv<<<800, 256, lds2, stream>>>(zb, bn1, g2, be2, wt3, cb3, za, bn2, 256, 0);
  k_conv<<<800, 256, lds2, stream>>>(za, bn2, g3, be3, wt4, cb4, zb, bn3, 256, 0);

  const int ldsa = 32 * 328 * 2;   // 20992 B
  k_ac<<<800, 256, ldsa, stream>>>(zb, bn3, g4, be4, wabf, hc, b1, Abf, Cbf);

  const int ldsm = 49152 * 2 + 256 * 4;            // 99328 B: W frags + b2/b3
  k_mlp<<<256, 1024, ldsm, stream>>>(Abf, Cbf, wmlp, b2, b3, b4, sbuf);
  k_final<<<32, 256, 0, stream>>>(sbuf, F1, fb1, F2, fb2, (float*)d_out);
}